// Round 9
// baseline (174.166 us; speedup 1.0000x reference)
//
#include <hip/hip_runtime.h>
#include <hip/hip_fp16.h>
#include <cmath>

namespace {

typedef float    vf4 __attribute__((ext_vector_type(4)));
typedef unsigned uv2 __attribute__((ext_vector_type(2)));

constexpr int kN = 524288;
constexpr int kL = 16;
constexpr int kCapLog2 = 19;
constexpr int kCap = 1 << kCapLog2;
constexpr int kCapMask = kCap - 1;
constexpr unsigned kHashMult = 2531011u;

constexpr int kPB  = kN / 256;       // 2048 point-blocks total
// thirds of the point-blocks
constexpr int kT0 = 682, kT1 = 682, kT2 = 684;
constexpr int kOffA = 0, kOffB = kT0, kOffC = kT0 + kT1;

// Dense key-box geometry for levels 0..3.
constexpr int cD[4][3]   = {{ 8, 8, 6},{10,10, 9},{13,12,10},{17,16,14}};
constexpr int cB[4][3]   = {{-4,-16,-16},{-4,-20,-24},{-4,-24,-28},{-4,-32,-40}};
constexpr int cOff[4]    = {0, 1536, 5136, 11376};
constexpr int kDenseCnt  = 26608;    // levels 0..3

// mega1 geometry: fine456 (3*2048) : conv 7-15 (9216) interleaved 2:3, + build
constexpr int kMegaMain  = 15360;    // 5 * 3072
constexpr int kBuildBlks = 104;
constexpr int kConvBaseF4 = 7 * (kCap * 2 / 4);

struct ScaleArr { float s[kL]; };

// ---------------- shared per-thread math (identical numerics since R1) -----
__device__ __forceinline__ void permuto_point(
    float x0, float x1, float x2, int rem0[4], int rank[4], float w[4])
{
    const float E00 = (float)( 0.70710678118654752440);
    const float E01 = (float)( 0.40824829046386301637);
    const float E02 = (float)( 0.28867513459481288225);
    const float E10 = (float)(-0.70710678118654752440);
    const float E21 = (float)(-2.0 * 0.40824829046386301637);
    const float E32 = (float)(-3.0 * 0.28867513459481288225);

    float elev[4];
    elev[0] = E00 * x0 + E01 * x1 + E02 * x2;
    elev[1] = E10 * x0 + E01 * x1 + E02 * x2;
    elev[2] =            E21 * x1 + E02 * x2;
    elev[3] =                       E32 * x2;

    float rem0f[4], di[4];
    #pragma unroll
    for (int v = 0; v < 4; ++v) {
        rem0f[v] = rintf(elev[v] * 0.25f) * 4.0f;
        di[v]    = elev[v] - rem0f[v];
    }
    const int sums = (int)((((rem0f[0] + rem0f[1]) + rem0f[2]) + rem0f[3]) * 0.25f);

    #pragma unroll
    for (int a = 0; a < 4; ++a) {
        int r = 0;
        #pragma unroll
        for (int b = 0; b < 4; ++b)
            r += (di[b] > di[a]) || (di[b] == di[a] && b < a);
        rank[a] = r + sums;
        rem0[a] = (int)rem0f[a];
    }
    #pragma unroll
    for (int v = 0; v < 4; ++v) {
        if (rank[v] < 0)      { rank[v] += 4; rem0[v] += 4; }
        else if (rank[v] > 3) { rank[v] -= 4; rem0[v] -= 4; }
    }

    float dbr[4];
    #pragma unroll
    for (int v = 0; v < 4; ++v)
        dbr[rank[v] & 3] = (elev[v] - (float)rem0[v]) * 0.25f;

    w[0] = (1.0f + dbr[3]) - dbr[0];
    w[1] = dbr[2] - dbr[3];
    w[2] = dbr[1] - dbr[2];
    w[3] = dbr[0] - dbr[1];
}

// ---- fine fp16 gather job for one (level, point) --------------------------
__device__ __forceinline__ void fine_job(
    const float* __restrict__ pos, const unsigned* __restrict__ tab,
    unsigned* __restrict__ out_t16, const ScaleArr& sc, int level, int n)
{
    const float s  = sc.s[level];
    const float x0 = __builtin_nontemporal_load(pos + 3 * n + 0) * s;
    const float x1 = __builtin_nontemporal_load(pos + 3 * n + 1) * s;
    const float x2 = __builtin_nontemporal_load(pos + 3 * n + 2) * s;

    int rem0[4], rank[4];
    float w[4];
    permuto_point(x0, x1, x2, rem0, rank, w);

    const unsigned* __restrict__ t = tab + ((size_t)level << kCapLog2);
    int hidx[4];
    #pragma unroll
    for (int k = 0; k < 4; ++k) {
        int h = 0;
        #pragma unroll
        for (int i = 0; i < 3; ++i) {
            const int key = rem0[i] + k - 4 * (rank[i] > 3 - k);
            h = (int)((unsigned)(h + key) * kHashMult);
        }
        hidx[k] = h & kCapMask;
    }
    unsigned e[4];
    #pragma unroll
    for (int k = 0; k < 4; ++k) e[k] = t[hidx[k]];

    float o0 = 0.0f, o1 = 0.0f;
    #pragma unroll
    for (int k = 0; k < 4; ++k) {
        const __half2 hv = *reinterpret_cast<const __half2*>(&e[k]);
        o0 += w[k] * __low2float(hv);
        o1 += w[k] * __high2float(hv);
    }
    const __half2 po = __floats2half2_rn(o0, o1);
    __builtin_nontemporal_store(*reinterpret_cast<const unsigned*>(&po),
                                out_t16 + ((size_t)level << kCapLog2) + n);
}

// ---- coarse job: levels 0..3 from dense global tables (L1/L2-resident) ----
__device__ __forceinline__ void coarse_job(
    const float* __restrict__ pos, const unsigned* __restrict__ dense,
    unsigned* __restrict__ out_t16, const ScaleArr& sc, int n)
{
    const float p0 = __builtin_nontemporal_load(pos + 3 * n + 0);
    const float p1 = __builtin_nontemporal_load(pos + 3 * n + 1);
    const float p2 = __builtin_nontemporal_load(pos + 3 * n + 2);

    #pragma unroll 1
    for (int l = 0; l < 4; ++l) {
        const float s = sc.s[l];
        int rem0[4], rank[4];
        float w[4];
        permuto_point(p0 * s, p1 * s, p2 * s, rem0, rank, w);

        const unsigned* __restrict__ dl = dense + cOff[l];
        unsigned ev[4];
        #pragma unroll
        for (int k = 0; k < 4; ++k) {
            const int i0 = (rem0[0] - 4 * (rank[0] > 3 - k) - cB[l][0]) >> 2;
            const int i1 = (rem0[1] - 4 * (rank[1] > 3 - k) - cB[l][1]) >> 2;
            const int i2 = (rem0[2] - 4 * (rank[2] > 3 - k) - cB[l][2]) >> 2;
            ev[k] = dl[((k * cD[l][0] + i0) * cD[l][1] + i1) * cD[l][2] + i2];
        }
        float o0 = 0.0f, o1 = 0.0f;
        #pragma unroll
        for (int k = 0; k < 4; ++k) {
            const __half2 hv = *reinterpret_cast<const __half2*>(&ev[k]);
            o0 += w[k] * __low2float(hv);
            o1 += w[k] * __high2float(hv);
        }
        const __half2 po = __floats2half2_rn(o0, o1);
        __builtin_nontemporal_store(*reinterpret_cast<const unsigned*>(&po),
                                    out_t16 + ((size_t)l << kCapLog2) + n);
    }
}

// ---- transpose job: point-block pb (256 pts) -> [point][32 floats] --------
__device__ __forceinline__ void transpose_job(
    const unsigned* __restrict__ out_t16, vf4* __restrict__ out4,
    int pb, unsigned (*tile)[17])
{
    const int t  = threadIdx.x;
    const int p0 = pb * 256;

    #pragma unroll
    for (int l = 0; l < kL; ++l)
        tile[t][l] = __builtin_nontemporal_load(out_t16 + ((size_t)l << kCapLog2) + p0 + t);
    __syncthreads();

    const size_t base = (size_t)p0 * 8;
    #pragma unroll
    for (int j = 0; j < 4; ++j) {
        const int idx = j * 256 + t;
        const int p = idx >> 2, q = idx & 3;
        float f[8];
        #pragma unroll
        for (int i = 0; i < 4; ++i) {
            const unsigned u = tile[p][4 * q + i];
            const __half2 hv = *reinterpret_cast<const __half2*>(&u);
            f[2 * i + 0] = __low2float(hv);
            f[2 * i + 1] = __high2float(hv);
        }
        vf4 a, c;
        a.x = f[0]; a.y = f[1]; a.z = f[2]; a.w = f[3];
        c.x = f[4]; c.y = f[5]; c.z = f[6]; c.w = f[7];
        out4[base + (size_t)p * 8 + 2 * q + 0] = a;
        out4[base + (size_t)p * 8 + 2 * q + 1] = c;
    }
}

// ---- K1 mega: fine levels 4-6 (direct f32) ∥ conv 7-15 ∥ build_dense ------
__global__ __launch_bounds__(256) void mega1(
    const float* __restrict__ pos,
    const float* __restrict__ params,
    unsigned* __restrict__ tab,
    unsigned* __restrict__ out_t16,
    unsigned* __restrict__ dense,
    ScaleArr sc)
{
    const int b = blockIdx.x;
    if (b < kMegaMain) {
        const int q = b / 5, r = b % 5;
        if (r < 2) {
            const int idx   = q * 2 + r;            // 0..6143
            const int level = 4 + (idx >> 11);
            const int n     = ((idx & 2047) << 8) + threadIdx.x;

            const float s  = sc.s[level];
            const float x0 = __builtin_nontemporal_load(pos + 3 * n + 0) * s;
            const float x1 = __builtin_nontemporal_load(pos + 3 * n + 1) * s;
            const float x2 = __builtin_nontemporal_load(pos + 3 * n + 2) * s;

            int rem0[4], rank[4];
            float w[4];
            permuto_point(x0, x1, x2, rem0, rank, w);

            const float2* __restrict__ t2 =
                (const float2*)params + ((size_t)level << kCapLog2);
            int hidx[4];
            #pragma unroll
            for (int k = 0; k < 4; ++k) {
                int h = 0;
                #pragma unroll
                for (int i = 0; i < 3; ++i) {
                    const int key = rem0[i] + k - 4 * (rank[i] > 3 - k);
                    h = (int)((unsigned)(h + key) * kHashMult);
                }
                hidx[k] = h & kCapMask;
            }
            float2 f[4];
            #pragma unroll
            for (int k = 0; k < 4; ++k) f[k] = t2[hidx[k]];

            float o0 = 0.0f, o1 = 0.0f;
            #pragma unroll
            for (int k = 0; k < 4; ++k) { o0 += w[k] * f[k].x; o1 += w[k] * f[k].y; }

            const __half2 po = __floats2half2_rn(o0, o1);
            __builtin_nontemporal_store(*reinterpret_cast<const unsigned*>(&po),
                                        out_t16 + ((size_t)level << kCapLog2) + n);
        } else {
            const int i  = q * 3 + (r - 2);         // 0..9215
            const int jj = kConvBaseF4 + i * 256 + threadIdx.x;
            vf4 v = __builtin_nontemporal_load((const vf4*)params + jj);
            __half2 a = __floats2half2_rn(v.x, v.y);
            __half2 c = __floats2half2_rn(v.z, v.w);
            uv2 o;
            o.x = *reinterpret_cast<unsigned*>(&a);
            o.y = *reinterpret_cast<unsigned*>(&c);
            __builtin_nontemporal_store(o, (uv2*)tab + jj);
        }
    } else {
        const int e = (b - kMegaMain) * 256 + threadIdx.x;
        if (e >= kDenseCnt) return;
        int l, r;
        if      (e < cOff[1]) { l = 0; r = e; }
        else if (e < cOff[2]) { l = 1; r = e - cOff[1]; }
        else if (e < cOff[3]) { l = 2; r = e - cOff[2]; }
        else                  { l = 3; r = e - cOff[3]; }
        const int d0 = cD[l][0], d1 = cD[l][1], d2 = cD[l][2];
        const int per = d0 * d1 * d2;
        int rr = r;
        const int k  = rr / per;  rr -= k * per;
        const int i0 = rr / (d1 * d2); rr -= i0 * (d1 * d2);
        const int i1 = rr / d2;
        const int i2 = rr - i1 * d2;

        const int key0 = cB[l][0] + 4 * i0 + k;
        const int key1 = cB[l][1] + 4 * i1 + k;
        const int key2 = cB[l][2] + 4 * i2 + k;
        int h = 0;
        h = (int)((unsigned)(h + key0) * kHashMult);
        h = (int)((unsigned)(h + key1) * kHashMult);
        h = (int)((unsigned)(h + key2) * kHashMult);
        const size_t entry = ((size_t)l << kCapLog2) + (h & kCapMask);
        const __half2 hv = __floats2half2_rn(params[entry * 2], params[entry * 2 + 1]);
        dense[e] = *reinterpret_cast<const unsigned*>(&hv);
    }
}

// ---- K2: coarse (all points, FIRST = hidden) + fine 7..15 (third A) -------
__global__ __launch_bounds__(256, 8) void gatherA(
    const float* __restrict__ pos,
    const unsigned* __restrict__ tab,
    const unsigned* __restrict__ dense,
    unsigned* __restrict__ out_t16,
    ScaleArr sc)
{
    const int b = blockIdx.x;
    if (b < kPB) {
        coarse_job(pos, dense, out_t16, sc, b * 256 + threadIdx.x);
    } else if (b < kPB + 8 * kT0) {
        const int q = b - kPB;
        const int level = 7 + (q & 7);              // XCD x owns level 7+x
        const int n = ((kOffA + (q >> 3)) << 8) + threadIdx.x;
        fine_job(pos, tab, out_t16, sc, level, n);
    } else {
        const int q = b - kPB - 8 * kT0;            // level-15 tail
        const int n = ((kOffA + q) << 8) + threadIdx.x;
        fine_job(pos, tab, out_t16, sc, 15, n);
    }
}

// ---- K3: transpose(A) FIRST (hidden) + fine 7..15 (third B) ---------------
__global__ __launch_bounds__(256, 8) void gatherB(
    const float* __restrict__ pos,
    const unsigned* __restrict__ tab,
    unsigned* __restrict__ out_t16,
    vf4* __restrict__ out4,
    ScaleArr sc)
{
    __shared__ unsigned tile[256][17];   // 17.4 KB x 8 blocks = 139 KB/CU: OK
    const int b = blockIdx.x;
    if (b < kT0) {
        transpose_job(out_t16, out4, kOffA + b, tile);
    } else if (b < kT0 + 8 * kT1) {
        const int q = b - kT0;
        const int level = 7 + (q & 7);
        const int n = ((kOffB + (q >> 3)) << 8) + threadIdx.x;
        fine_job(pos, tab, out_t16, sc, level, n);
    } else {
        const int q = b - kT0 - 8 * kT1;
        const int n = ((kOffB + q) << 8) + threadIdx.x;
        fine_job(pos, tab, out_t16, sc, 15, n);
    }
}

// ---- K4: transpose(B) FIRST (hidden) + fine 7..15 (third C) ---------------
__global__ __launch_bounds__(256, 8) void gatherC(
    const float* __restrict__ pos,
    const unsigned* __restrict__ tab,
    unsigned* __restrict__ out_t16,
    vf4* __restrict__ out4,
    ScaleArr sc)
{
    __shared__ unsigned tile[256][17];
    const int b = blockIdx.x;
    if (b < kT1) {
        transpose_job(out_t16, out4, kOffB + b, tile);
    } else if (b < kT1 + 8 * kT2) {
        const int q = b - kT1;
        const int level = 7 + (q & 7);
        const int n = ((kOffC + (q >> 3)) << 8) + threadIdx.x;
        fine_job(pos, tab, out_t16, sc, level, n);
    } else {
        const int q = b - kT1 - 8 * kT2;
        const int n = ((kOffC + q) << 8) + threadIdx.x;
        fine_job(pos, tab, out_t16, sc, 15, n);
    }
}

// ---- K5: transpose(C) -----------------------------------------------------
__global__ __launch_bounds__(256) void transposeC(
    const unsigned* __restrict__ out_t16, vf4* __restrict__ out4)
{
    __shared__ unsigned tile[256][17];
    transpose_job(out_t16, out4, kOffC + blockIdx.x, tile);
}

// ---------------- fallback (R1 kernel) if ws is too small ------------------
__global__ __launch_bounds__(256) void permuto_fwd(
    const float* __restrict__ pos,
    const float* __restrict__ params,
    float* __restrict__ out,
    ScaleArr sc)
{
    const int gid = blockIdx.x * 256 + threadIdx.x;
    const int l = gid & (kL - 1);
    const int n = gid >> 4;

    const float s  = sc.s[l];
    const float x0 = pos[3 * n + 0] * s;
    const float x1 = pos[3 * n + 1] * s;
    const float x2 = pos[3 * n + 2] * s;

    int rem0[4], rank[4];
    float w[4];
    permuto_point(x0, x1, x2, rem0, rank, w);

    const float2* __restrict__ tab = (const float2*)params + ((size_t)l << kCapLog2);
    float o0 = 0.0f, o1 = 0.0f;
    #pragma unroll
    for (int k = 0; k < 4; ++k) {
        int h = 0;
        #pragma unroll
        for (int i = 0; i < 3; ++i) {
            const int key = rem0[i] + k - 4 * (rank[i] > 3 - k);
            h = (int)((unsigned)(h + key) * kHashMult);
        }
        const float2 f = tab[h & kCapMask];
        o0 += w[k] * f.x;
        o1 += w[k] * f.y;
    }
    ((float2*)out)[(n << 4) + l] = make_float2(o0, o1);
}

} // namespace

extern "C" void kernel_launch(void* const* d_in, const int* in_sizes, int n_in,
                              void* d_out, int out_size, void* d_ws, size_t ws_size,
                              hipStream_t stream) {
    const float* pos    = (const float*)d_in[0];
    const float* params = (const float*)d_in[1];
    float* out          = (float*)d_out;

    ScaleArr sc;
    for (int l = 0; l < kL; ++l)
        sc.s[l] = (float)(16.0 * pow(128.0, (double)l / 15.0));

    const size_t tab_bytes   = (size_t)kL * kCap * 4;   // fp16 table: 32 MiB
    const size_t outt_bytes  = (size_t)kL * kN * 4;     // fp16 level-major out: 32 MiB
    const size_t dense_bytes = (size_t)kDenseCnt * 4;   // ~104 KiB

    if (ws_size >= tab_bytes + outt_bytes + dense_bytes) {
        unsigned* tab     = (unsigned*)d_ws;
        unsigned* out_t16 = (unsigned*)((char*)d_ws + tab_bytes);
        unsigned* dense   = (unsigned*)((char*)d_ws + tab_bytes + outt_bytes);

        mega1<<<kMegaMain + kBuildBlks, 256, 0, stream>>>(pos, params, tab, out_t16, dense, sc);
        gatherA<<<kPB + 9 * kT0, 256, 0, stream>>>(pos, tab, dense, out_t16, sc);
        gatherB<<<kT0 + 9 * kT1, 256, 0, stream>>>(pos, tab, out_t16, (vf4*)out, sc);
        gatherC<<<kT1 + 9 * kT2, 256, 0, stream>>>(pos, tab, out_t16, (vf4*)out, sc);
        transposeC<<<kT2, 256, 0, stream>>>(out_t16, (vf4*)out);
    } else {
        permuto_fwd<<<(kN * kL) / 256, 256, 0, stream>>>(pos, params, out, sc);
    }
}

// Round 10
// 165.368 us; speedup vs baseline: 1.0532x; 1.0532x over previous
//
#include <hip/hip_runtime.h>
#include <hip/hip_fp16.h>
#include <cmath>

namespace {

typedef float    vf4 __attribute__((ext_vector_type(4)));
typedef unsigned uv2 __attribute__((ext_vector_type(2)));

constexpr int kN = 524288;
constexpr int kL = 16;
constexpr int kCapLog2 = 19;
constexpr int kCap = 1 << kCapLog2;
constexpr int kCapMask = kCap - 1;
constexpr unsigned kHashMult = 2531011u;

// Dense key-box geometry for levels 0..3.
constexpr int cD[4][3]   = {{ 8, 8, 6},{10,10, 9},{13,12,10},{17,16,14}};
constexpr int cB[4][3]   = {{-4,-16,-16},{-4,-20,-24},{-4,-24,-28},{-4,-32,-40}};
constexpr int cOff[4]    = {0, 1536, 5136, 11376};
constexpr int kDenseCnt  = 26608;    // levels 0..3

// mega1 geometry: fine456 (3*2048) : conv 7-15 (9216) interleaved 2:3, + build
constexpr int kMegaMain  = 15360;    // 5 * 3072
constexpr int kBuildBlks = 104;
constexpr int kConvBaseF4 = 7 * (kCap * 2 / 4);

struct ScaleArr { float s[kL]; };

// ---------------- shared per-thread math (identical numerics since R1) -----
__device__ __forceinline__ void permuto_point(
    float x0, float x1, float x2, int rem0[4], int rank[4], float w[4])
{
    const float E00 = (float)( 0.70710678118654752440);
    const float E01 = (float)( 0.40824829046386301637);
    const float E02 = (float)( 0.28867513459481288225);
    const float E10 = (float)(-0.70710678118654752440);
    const float E21 = (float)(-2.0 * 0.40824829046386301637);
    const float E32 = (float)(-3.0 * 0.28867513459481288225);

    float elev[4];
    elev[0] = E00 * x0 + E01 * x1 + E02 * x2;
    elev[1] = E10 * x0 + E01 * x1 + E02 * x2;
    elev[2] =            E21 * x1 + E02 * x2;
    elev[3] =                       E32 * x2;

    float rem0f[4], di[4];
    #pragma unroll
    for (int v = 0; v < 4; ++v) {
        rem0f[v] = rintf(elev[v] * 0.25f) * 4.0f;
        di[v]    = elev[v] - rem0f[v];
    }
    const int sums = (int)((((rem0f[0] + rem0f[1]) + rem0f[2]) + rem0f[3]) * 0.25f);

    #pragma unroll
    for (int a = 0; a < 4; ++a) {
        int r = 0;
        #pragma unroll
        for (int b = 0; b < 4; ++b)
            r += (di[b] > di[a]) || (di[b] == di[a] && b < a);
        rank[a] = r + sums;
        rem0[a] = (int)rem0f[a];
    }
    #pragma unroll
    for (int v = 0; v < 4; ++v) {
        if (rank[v] < 0)      { rank[v] += 4; rem0[v] += 4; }
        else if (rank[v] > 3) { rank[v] -= 4; rem0[v] -= 4; }
    }

    float dbr[4];
    #pragma unroll
    for (int v = 0; v < 4; ++v)
        dbr[rank[v] & 3] = (elev[v] - (float)rem0[v]) * 0.25f;

    w[0] = (1.0f + dbr[3]) - dbr[0];
    w[1] = dbr[2] - dbr[3];
    w[2] = dbr[1] - dbr[2];
    w[3] = dbr[0] - dbr[1];
}

// ---- fine fp16 gather job for one (level, point) --------------------------
__device__ __forceinline__ void fine_job(
    const float* __restrict__ pos, const unsigned* __restrict__ tab,
    unsigned* __restrict__ out_t16, const ScaleArr& sc, int level, int n)
{
    const float s  = sc.s[level];
    const float x0 = __builtin_nontemporal_load(pos + 3 * n + 0) * s;
    const float x1 = __builtin_nontemporal_load(pos + 3 * n + 1) * s;
    const float x2 = __builtin_nontemporal_load(pos + 3 * n + 2) * s;

    int rem0[4], rank[4];
    float w[4];
    permuto_point(x0, x1, x2, rem0, rank, w);

    const unsigned* __restrict__ t = tab + ((size_t)level << kCapLog2);
    int hidx[4];
    #pragma unroll
    for (int k = 0; k < 4; ++k) {
        int h = 0;
        #pragma unroll
        for (int i = 0; i < 3; ++i) {
            const int key = rem0[i] + k - 4 * (rank[i] > 3 - k);
            h = (int)((unsigned)(h + key) * kHashMult);
        }
        hidx[k] = h & kCapMask;
    }
    unsigned e[4];
    #pragma unroll
    for (int k = 0; k < 4; ++k) e[k] = t[hidx[k]];

    float o0 = 0.0f, o1 = 0.0f;
    #pragma unroll
    for (int k = 0; k < 4; ++k) {
        const __half2 hv = *reinterpret_cast<const __half2*>(&e[k]);
        o0 += w[k] * __low2float(hv);
        o1 += w[k] * __high2float(hv);
    }
    const __half2 po = __floats2half2_rn(o0, o1);
    __builtin_nontemporal_store(*reinterpret_cast<const unsigned*>(&po),
                                out_t16 + ((size_t)level << kCapLog2) + n);
}

// ---- coarse job: levels 0..3 from dense global tables (L1/L2-resident) ----
__device__ __forceinline__ void coarse_job(
    const float* __restrict__ pos, const unsigned* __restrict__ dense,
    unsigned* __restrict__ out_t16, const ScaleArr& sc, int n)
{
    const float p0 = __builtin_nontemporal_load(pos + 3 * n + 0);
    const float p1 = __builtin_nontemporal_load(pos + 3 * n + 1);
    const float p2 = __builtin_nontemporal_load(pos + 3 * n + 2);

    #pragma unroll 1
    for (int l = 0; l < 4; ++l) {
        const float s = sc.s[l];
        int rem0[4], rank[4];
        float w[4];
        permuto_point(p0 * s, p1 * s, p2 * s, rem0, rank, w);

        const unsigned* __restrict__ dl = dense + cOff[l];
        unsigned ev[4];
        #pragma unroll
        for (int k = 0; k < 4; ++k) {
            const int i0 = (rem0[0] - 4 * (rank[0] > 3 - k) - cB[l][0]) >> 2;
            const int i1 = (rem0[1] - 4 * (rank[1] > 3 - k) - cB[l][1]) >> 2;
            const int i2 = (rem0[2] - 4 * (rank[2] > 3 - k) - cB[l][2]) >> 2;
            ev[k] = dl[((k * cD[l][0] + i0) * cD[l][1] + i1) * cD[l][2] + i2];
        }
        float o0 = 0.0f, o1 = 0.0f;
        #pragma unroll
        for (int k = 0; k < 4; ++k) {
            const __half2 hv = *reinterpret_cast<const __half2*>(&ev[k]);
            o0 += w[k] * __low2float(hv);
            o1 += w[k] * __high2float(hv);
        }
        const __half2 po = __floats2half2_rn(o0, o1);
        __builtin_nontemporal_store(*reinterpret_cast<const unsigned*>(&po),
                                    out_t16 + ((size_t)l << kCapLog2) + n);
    }
}

// ---- K1 mega: fine levels 4-6 (direct f32) ∥ conv 7-15 ∥ build_dense ------
__global__ __launch_bounds__(256) void mega1(
    const float* __restrict__ pos,
    const float* __restrict__ params,
    unsigned* __restrict__ tab,
    unsigned* __restrict__ out_t16,
    unsigned* __restrict__ dense,
    ScaleArr sc)
{
    const int b = blockIdx.x;
    if (b < kMegaMain) {
        const int q = b / 5, r = b % 5;
        if (r < 2) {
            const int idx   = q * 2 + r;            // 0..6143
            const int level = 4 + (idx >> 11);
            const int n     = ((idx & 2047) << 8) + threadIdx.x;

            const float s  = sc.s[level];
            const float x0 = __builtin_nontemporal_load(pos + 3 * n + 0) * s;
            const float x1 = __builtin_nontemporal_load(pos + 3 * n + 1) * s;
            const float x2 = __builtin_nontemporal_load(pos + 3 * n + 2) * s;

            int rem0[4], rank[4];
            float w[4];
            permuto_point(x0, x1, x2, rem0, rank, w);

            const float2* __restrict__ t2 =
                (const float2*)params + ((size_t)level << kCapLog2);
            int hidx[4];
            #pragma unroll
            for (int k = 0; k < 4; ++k) {
                int h = 0;
                #pragma unroll
                for (int i = 0; i < 3; ++i) {
                    const int key = rem0[i] + k - 4 * (rank[i] > 3 - k);
                    h = (int)((unsigned)(h + key) * kHashMult);
                }
                hidx[k] = h & kCapMask;
            }
            float2 f[4];
            #pragma unroll
            for (int k = 0; k < 4; ++k) f[k] = t2[hidx[k]];

            float o0 = 0.0f, o1 = 0.0f;
            #pragma unroll
            for (int k = 0; k < 4; ++k) { o0 += w[k] * f[k].x; o1 += w[k] * f[k].y; }

            const __half2 po = __floats2half2_rn(o0, o1);
            __builtin_nontemporal_store(*reinterpret_cast<const unsigned*>(&po),
                                        out_t16 + ((size_t)level << kCapLog2) + n);
        } else {
            const int i  = q * 3 + (r - 2);         // 0..9215
            const int jj = kConvBaseF4 + i * 256 + threadIdx.x;
            vf4 v = __builtin_nontemporal_load((const vf4*)params + jj);
            __half2 a = __floats2half2_rn(v.x, v.y);
            __half2 c = __floats2half2_rn(v.z, v.w);
            uv2 o;
            o.x = *reinterpret_cast<unsigned*>(&a);
            o.y = *reinterpret_cast<unsigned*>(&c);
            __builtin_nontemporal_store(o, (uv2*)tab + jj);
        }
    } else {
        const int e = (b - kMegaMain) * 256 + threadIdx.x;
        if (e >= kDenseCnt) return;
        int l, r;
        if      (e < cOff[1]) { l = 0; r = e; }
        else if (e < cOff[2]) { l = 1; r = e - cOff[1]; }
        else if (e < cOff[3]) { l = 2; r = e - cOff[2]; }
        else                  { l = 3; r = e - cOff[3]; }
        const int d0 = cD[l][0], d1 = cD[l][1], d2 = cD[l][2];
        const int per = d0 * d1 * d2;
        int rr = r;
        const int k  = rr / per;  rr -= k * per;
        const int i0 = rr / (d1 * d2); rr -= i0 * (d1 * d2);
        const int i1 = rr / d2;
        const int i2 = rr - i1 * d2;

        const int key0 = cB[l][0] + 4 * i0 + k;
        const int key1 = cB[l][1] + 4 * i1 + k;
        const int key2 = cB[l][2] + 4 * i2 + k;
        int h = 0;
        h = (int)((unsigned)(h + key0) * kHashMult);
        h = (int)((unsigned)(h + key1) * kHashMult);
        h = (int)((unsigned)(h + key2) * kHashMult);
        const size_t entry = ((size_t)l << kCapLog2) + (h & kCapMask);
        const __half2 hv = __floats2half2_rn(params[entry * 2], params[entry * 2 + 1]);
        dense[e] = *reinterpret_cast<const unsigned*>(&hv);
    }
}

// ---- K2: fine 7..15 with coarse interleaved 9:1 per-XCD stream ------------
// Per-XCD stream j = b>>3 (xcd = b&7), 2560 entries:
//   j%10==9        -> coarse point-block (xcd*256 + j/10)
//   else fj=g*9+r  -> fj<2048: level 7+xcd, point-block fj
//                     fj>=2048: level 15, point-block (fj-2048)+(xcd<<8)
// Coarse (L1-resident gathers + VALU) rides inside the MSHR-stall shadow of
// the fine gather wall instead of running as an exposed tail (R7) or an
// exposed prologue (R9). Zero LDS, VGPR<=64: no occupancy contamination.
__global__ __launch_bounds__(256, 8) void fine715i(
    const float* __restrict__ pos,
    const unsigned* __restrict__ tab,
    const unsigned* __restrict__ dense,
    unsigned* __restrict__ out_t16,
    ScaleArr sc)
{
    const int b   = blockIdx.x;
    const int xcd = b & 7;
    const int j   = b >> 3;            // 0..2559
    const int g   = j / 10;
    const int r   = j - 10 * g;

    if (r == 9) {
        coarse_job(pos, dense, out_t16, sc, (((xcd << 8) + g) << 8) + threadIdx.x);
    } else {
        const int fj = g * 9 + r;      // 0..2303
        if (fj < 2048) {
            const int n = (fj << 8) + threadIdx.x;
            fine_job(pos, tab, out_t16, sc, 7 + xcd, n);
        } else {
            const int c = (fj - 2048) + (xcd << 8);
            const int n = (c << 8) + threadIdx.x;
            fine_job(pos, tab, out_t16, sc, 15, n);
        }
    }
}

// ---- K3: [level][point] fp16 -> [point][32 floats]; u32 LDS tile (17.4 KB) -
__global__ __launch_bounds__(256) void transpose16(
    const unsigned* __restrict__ out_t16, vf4* __restrict__ out4)
{
    __shared__ unsigned tile[256][17];      // +1 pad: stride 17 (gcd 32 = 1)
    const int t  = threadIdx.x;
    const int p0 = blockIdx.x * 256;

    #pragma unroll
    for (int l = 0; l < kL; ++l)
        tile[t][l] = __builtin_nontemporal_load(out_t16 + ((size_t)l << kCapLog2) + p0 + t);
    __syncthreads();

    const size_t base = (size_t)p0 * 8;     // float4 index of block's output
    #pragma unroll
    for (int j = 0; j < 4; ++j) {
        const int idx = j * 256 + t;        // 0..1023 = 256 pts * 4 quarters
        const int p = idx >> 2, q = idx & 3;
        float f[8];
        #pragma unroll
        for (int i = 0; i < 4; ++i) {
            const unsigned u = tile[p][4 * q + i];
            const __half2 hv = *reinterpret_cast<const __half2*>(&u);
            f[2 * i + 0] = __low2float(hv);
            f[2 * i + 1] = __high2float(hv);
        }
        vf4 a, c;
        a.x = f[0]; a.y = f[1]; a.z = f[2]; a.w = f[3];
        c.x = f[4]; c.y = f[5]; c.z = f[6]; c.w = f[7];
        out4[base + (size_t)p * 8 + 2 * q + 0] = a;
        out4[base + (size_t)p * 8 + 2 * q + 1] = c;
    }
}

// ---------------- fallback (R1 kernel) if ws is too small ------------------
__global__ __launch_bounds__(256) void permuto_fwd(
    const float* __restrict__ pos,
    const float* __restrict__ params,
    float* __restrict__ out,
    ScaleArr sc)
{
    const int gid = blockIdx.x * 256 + threadIdx.x;
    const int l = gid & (kL - 1);
    const int n = gid >> 4;

    const float s  = sc.s[l];
    const float x0 = pos[3 * n + 0] * s;
    const float x1 = pos[3 * n + 1] * s;
    const float x2 = pos[3 * n + 2] * s;

    int rem0[4], rank[4];
    float w[4];
    permuto_point(x0, x1, x2, rem0, rank, w);

    const float2* __restrict__ tab = (const float2*)params + ((size_t)l << kCapLog2);
    float o0 = 0.0f, o1 = 0.0f;
    #pragma unroll
    for (int k = 0; k < 4; ++k) {
        int h = 0;
        #pragma unroll
        for (int i = 0; i < 3; ++i) {
            const int key = rem0[i] + k - 4 * (rank[i] > 3 - k);
            h = (int)((unsigned)(h + key) * kHashMult);
        }
        const float2 f = tab[h & kCapMask];
        o0 += w[k] * f.x;
        o1 += w[k] * f.y;
    }
    ((float2*)out)[(n << 4) + l] = make_float2(o0, o1);
}

} // namespace

extern "C" void kernel_launch(void* const* d_in, const int* in_sizes, int n_in,
                              void* d_out, int out_size, void* d_ws, size_t ws_size,
                              hipStream_t stream) {
    const float* pos    = (const float*)d_in[0];
    const float* params = (const float*)d_in[1];
    float* out          = (float*)d_out;

    ScaleArr sc;
    for (int l = 0; l < kL; ++l)
        sc.s[l] = (float)(16.0 * pow(128.0, (double)l / 15.0));

    const size_t tab_bytes   = (size_t)kL * kCap * 4;   // fp16 table: 32 MiB
    const size_t outt_bytes  = (size_t)kL * kN * 4;     // fp16 level-major out: 32 MiB
    const size_t dense_bytes = (size_t)kDenseCnt * 4;   // ~104 KiB

    if (ws_size >= tab_bytes + outt_bytes + dense_bytes) {
        unsigned* tab     = (unsigned*)d_ws;
        unsigned* out_t16 = (unsigned*)((char*)d_ws + tab_bytes);
        unsigned* dense   = (unsigned*)((char*)d_ws + tab_bytes + outt_bytes);

        mega1<<<kMegaMain + kBuildBlks, 256, 0, stream>>>(pos, params, tab, out_t16, dense, sc);
        fine715i<<<8 * 2560, 256, 0, stream>>>(pos, tab, dense, out_t16, sc);
        transpose16<<<kN / 256, 256, 0, stream>>>(out_t16, (vf4*)out);
    } else {
        permuto_fwd<<<(kN * kL) / 256, 256, 0, stream>>>(pos, params, out, sc);
    }
}